// Round 2
// baseline (279.781 us; speedup 1.0000x reference)
//
#include <hip/hip_runtime.h>
#include <math.h>

typedef __attribute__((ext_vector_type(8)))  short short8;   // 8 x bf16 (4 VGPR) MFMA operand
typedef __attribute__((ext_vector_type(16))) float float16;  // 32x32 MFMA accumulator

#define DEVI __device__ __forceinline__

DEVI short f2bf(float f) {                      // RNE float -> bf16 bits
    unsigned u = __float_as_uint(f);
    u = (u + 0x7fffu + ((u >> 16) & 1u)) >> 16;
    return (short)u;
}
DEVI unsigned pk2(float a, float b) {
    return (unsigned)(unsigned short)f2bf(a) | ((unsigned)(unsigned short)f2bf(b) << 16);
}
DEVI float16 mfma16(short8 a, short8 b, float16 c) {
    return __builtin_amdgcn_mfma_f32_32x32x16_bf16(a, b, c, 0, 0, 0);
}
// C/D row for reg r, half h: row = (r&3) + 8*(r>>2) + 4*h  [verified R1/R2]
DEVI int rowof(int r, int h) { return (r & 3) + 8 * (r >> 2) + 4 * h; }
DEVI short8 lds8(const short* p) { return *(const short8*)p; }
DEVI short8 gld8(const short* p) { return *(const short8*)p; }

// ---- ws layout (shorts): MFMA-native [ceil(K/16)][N][16] bf16 ----
#define W1T_OFF  0          // [23][512][16] (K=365 pad 368)
#define W2T_OFF  188416     // [32][256][16]
#define W3T_OFF  319488     // [16][128][16]
#define WC1T_OFF 352256     // [10][64][16]
#define WC2T_OFF 362496     // [4][32][16]
// big-ws additions:
#define XBF_OFF   364544ull   // x as bf16 [65536][368] (shorts), 16B-aligned rows
#define FEATB_OFF 24481792ull // feat as bf16 [65536][32] (shorts)
#define WS_NEED_BYTES ((FEATB_OFF + 65536ull * 32ull) * 2ull)   // 53,157,888 B

// ---------------- prep: weight transpose + (optionally) x->bf16 + moments/FEAT --
// blocks 0..357: weight transpose (verbatim prep_v2 logic)
// blocks 358..16741: 4 rows each (one wave per row): coalesced row read, bf16
//   pack to XBF, 64-lane shuffle-reduced moments, FEAT = stat@Ws+bs -> bf16 FEATB
__global__ void prep_all(const float* __restrict__ W1, const float* __restrict__ W2,
                         const float* __restrict__ W3, const float* __restrict__ Wc1,
                         const float* __restrict__ Wc2, const float* __restrict__ x,
                         const float* __restrict__ Wsf, const float* __restrict__ bsf,
                         short* __restrict__ ws) {
    __shared__ short T[16 * 72];
    int b = blockIdx.x, t = threadIdx.x;
    if (b >= 358) {
        // ---- x path ----
        int lane = t & 63;
        int row  = (b - 358) * 4 + (t >> 6);
        const float* xr = x + (size_t)row * 365;
        int c0 = lane * 8;                       // lanes 0..45 cover 0..367
        float v[8];
        float s1 = 0.f, s2 = 0.f, s3 = 0.f, s4 = 0.f, mn = 1e30f, mx = -1e30f;
        #pragma unroll
        for (int j = 0; j < 8; ++j) {
            int c = c0 + j;
            float f = (c < 365) ? xr[c] : 0.f;
            v[j] = f;
            if (c < 365) {
                float f2 = f * f;
                s1 += f; s2 += f2; s3 += f2 * f; s4 += f2 * f2;
                mn = fminf(mn, f); mx = fmaxf(mx, f);
            }
        }
        if (lane < 46) {
            short8 o;
            #pragma unroll
            for (int j = 0; j < 8; ++j) o[j] = f2bf(v[j]);
            *(short8*)(ws + XBF_OFF + (size_t)row * 368 + c0) = o;
        }
        #pragma unroll
        for (int off = 1; off <= 32; off <<= 1) {
            s1 += __shfl_xor(s1, off); s2 += __shfl_xor(s2, off);
            s3 += __shfl_xor(s3, off); s4 += __shfl_xor(s4, off);
            mn = fminf(mn, __shfl_xor(mn, off)); mx = fmaxf(mx, __shfl_xor(mx, off));
        }
        float mean  = s1 * (1.0f / 365.0f);
        float var1  = (s2 - 365.0f * mean * mean) * (1.0f / 364.0f);
        float sigma = sqrtf(var1);
        float m3 = (s3 - 3.0f * mean * s2) * (1.0f / 365.0f) + 2.0f * mean * mean * mean;
        float mm = mean * mean;
        float m4v = (s4 - 4.0f * mean * s3 + 6.0f * mm * s2) * (1.0f / 365.0f) - 3.0f * mm * mm;
        float sg2 = sigma * sigma;
        float st[6] = { mean, sigma, mn, mx,
                        m3 / (sigma * sg2 + 1e-8f), m4v / (sg2 * sg2 + 1e-8f) };
        int c = lane & 31;
        float fv = bsf[c];
        #pragma unroll
        for (int jj = 0; jj < 6; ++jj) fv += st[jj] * Wsf[jj * 32 + c];
        float fA = __shfl(fv, 2 * (lane & 15));
        float fB = __shfl(fv, 2 * (lane & 15) + 1);
        if (lane < 16)
            *(unsigned*)(ws + FEATB_OFF + (size_t)row * 32 + 2 * lane) = pk2(fA, fB);
        return;
    }
    // ---- weight transpose path (verbatim) ----
    const float* src; int K, N; size_t base; int kc, nb;
    if (b < 184)        {            src = W1;  K = 365; N = 512; base = W1T_OFF;  kc = b >> 3;  nb = b & 7; }
    else if (b < 312)   { int l = b - 184; src = W2;  K = 512; N = 256; base = W2T_OFF;  kc = l >> 2;  nb = l & 3; }
    else if (b < 344)   { int l = b - 312; src = W3;  K = 256; N = 128; base = W3T_OFF;  kc = l >> 1;  nb = l & 1; }
    else if (b < 354)   {            src = Wc1; K = 160; N = 64;  base = WC1T_OFF; kc = b - 344; nb = 0; }
    else                {            src = Wc2; K = 64;  N = 32;  base = WC2T_OFF; kc = b - 354; nb = 0; }
    int n = nb * 64 + (t & 63);
    int kr = t >> 6;
    #pragma unroll
    for (int i = 0; i < 4; ++i) {
        int krow = kr + 4 * i;
        int k = kc * 16 + krow;
        float v = (k < K && n < N) ? src[(size_t)k * N + n] : 0.f;
        T[krow * 72 + (t & 63)] = f2bf(v);
    }
    __syncthreads();
    int n2 = t >> 2, ksq = (t & 3) * 4;
    int ng = nb * 64 + n2;
    if (ng < N) {
        unsigned lo = (unsigned)(unsigned short)T[ksq * 72 + n2]
                    | ((unsigned)(unsigned short)T[(ksq + 1) * 72 + n2] << 16);
        unsigned hi = (unsigned)(unsigned short)T[(ksq + 2) * 72 + n2]
                    | ((unsigned)(unsigned short)T[(ksq + 3) * 72 + n2] << 16);
        uint2 d; d.x = lo; d.y = hi;
        *(uint2*)(ws + base + ((size_t)kc * N + ng) * 16 + ksq) = d;
    }
}

// ---------------- fused_v5 (big-ws): A from global bf16, barrier-lean ----------
// 8 waves, wave wv owns col-group 32*wv..+32 at each layer width step.
// No XT, no x-phase, no FEAT state: LDS = SB[64][264] (h1/h2 staging, 256-wide
// slabs staged by ALL 8 waves) + SEQ[64][136] + C1 + C2. 9 barriers total.
__global__ __launch_bounds__(512, 4)
void fused_v5(const float* __restrict__ b1f, const float* __restrict__ b2f,
              const float* __restrict__ b3f, const float* __restrict__ bc1f,
              const float* __restrict__ bc2f, const float* __restrict__ Wc3f,
              const float* __restrict__ bc3f,
              const short* __restrict__ wsw, float* __restrict__ out)
{
    __shared__ __align__(16) char smem[68864];
    short* SB  = (short*)smem;                  // [64][264]  33,792 B (h1/h2 slabs)
    short* SEQ = (short*)(smem + 33792);        // [64][136]  17,408 B
    short* C1  = (short*)(smem + 51200);        // [64][72]    9,216 B
    float* C2  = (float*)(smem + 60416);        // [64][33]f32 8,448 B

    const short* W1t   = wsw + W1T_OFF;
    const short* W2t   = wsw + W2T_OFF;
    const short* W3t   = wsw + W3T_OFF;
    const short* Wc1t  = wsw + WC1T_OFF;
    const short* Wc2t  = wsw + WC2T_OFF;
    const short* xbf   = wsw + XBF_OFF;
    const short* featb = wsw + FEATB_OFF;

    const int tid  = (int)threadIdx.x;
    const int lane = tid & 63;
    const int wv   = tid >> 6;       // 0..7 col-group (dup-free B)
    const int m    = lane & 31;
    const int h    = lane >> 5;
    const int rowBase = (int)blockIdx.x * 64;

    float bb1a = b1f[32 * wv + m];
    float bb1b = b1f[256 + 32 * wv + m];
    float bb2  = b2f[32 * wv + m];
    float bb3  = b3f[32 * (wv & 3) + m];

    // A fragments straight from global bf16 x (row stride 368 shorts, 16B lanes)
    const short* Ax0 = xbf + (size_t)(rowBase + m) * 368 + h * 8;
    const short* Ax1 = Ax0 + 32 * 368;

    float16 ha0, ha1;                           // h2 accum (rows 0-31 / 32-63)
    #pragma unroll
    for (int i = 0; i < 16; ++i) { ha0[i] = 0.f; ha1[i] = 0.f; }

    const short* A2p0 = SB + m * 264 + h * 8;
    const short* A2p1 = SB + (32 + m) * 264 + h * 8;
    const int stcol = 32 * wv + m;              // col in the 256-wide slab

    #pragma unroll
    for (int p = 0; p < 2; ++p) {
        // ---- G1: 23 K-chunks, A from global, B from W1t ----
        float16 ga0, ga1;
        #pragma unroll
        for (int i = 0; i < 16; ++i) { ga0[i] = 0.f; ga1[i] = 0.f; }
        const short* B1 = W1t + (256 * p + 32 * wv + m) * 16 + h * 8;
        #pragma unroll
        for (int kc = 0; kc < 23; ++kc) {
            short8 b  = gld8(B1 + kc * 8192);
            short8 a0 = gld8(Ax0 + kc * 16);
            short8 a1 = gld8(Ax1 + kc * 16);
            ga0 = mfma16(a0, b, ga0);
            ga1 = mfma16(a1, b, ga1);
        }
        // ---- stage full 256-wide h1 slab (all 8 waves) ----
        float bb = p ? bb1b : bb1a;
        __syncthreads();                        // prior SB consumers done
        #pragma unroll
        for (int r = 0; r < 16; ++r) {
            int rw = rowof(r, h);
            SB[rw * 264 + stcol]        = f2bf(fmaxf(ga0[r] + bb, 0.f));
            SB[(32 + rw) * 264 + stcol] = f2bf(fmaxf(ga1[r] + bb, 0.f));
        }
        __syncthreads();                        // slab staged
        // ---- G2: 16 K-chunks over this slab ----
        const short* B2 = W2t + p * 16 * 4096 + (32 * wv + m) * 16 + h * 8;
        #pragma unroll
        for (int i = 0; i < 16; ++i) {
            short8 b  = gld8(B2 + i * 4096);
            short8 a0 = lds8(A2p0 + i * 16);
            short8 a1 = lds8(A2p1 + i * 16);
            ha0 = mfma16(a0, b, ha0);
            ha1 = mfma16(a1, b, ha1);
        }
    }

    // ---- stage full h2 [64][256] then G3 in one shot (K=256) ----
    __syncthreads();                            // G2 SB reads done
    #pragma unroll
    for (int r = 0; r < 16; ++r) {
        int rw = rowof(r, h);
        SB[rw * 264 + stcol]        = f2bf(fmaxf(ha0[r] + bb2, 0.f));
        SB[(32 + rw) * 264 + stcol] = f2bf(fmaxf(ha1[r] + bb2, 0.f));
    }
    __syncthreads();                            // h2 staged

    // G3: all 8 waves active. cg3 = wv&3 (seq col-group), rh3 = wv>>2 (row half)
    const int cg3 = wv & 3, rh3 = wv >> 2;
    float16 g3;
    #pragma unroll
    for (int i = 0; i < 16; ++i) g3[i] = 0.f;
    const short* A3 = SB + (32 * rh3 + m) * 264 + h * 8;
    const short* B3 = W3t + (32 * cg3 + m) * 16 + h * 8;
    #pragma unroll
    for (int i = 0; i < 16; ++i) {
        short8 b = gld8(B3 + i * 2048);
        short8 a = lds8(A3 + i * 16);
        g3 = mfma16(a, b, g3);
    }
    // stage seq into SEQ (separate region -> no barrier needed before writes)
    #pragma unroll
    for (int r = 0; r < 16; ++r)
        SEQ[(32 * rh3 + rowof(r, h)) * 136 + 32 * cg3 + m] = f2bf(fmaxf(g3[r] + bb3, 0.f));
    __syncthreads();                            // seq staged

    // ---- G4: c1 = relu([seq|feat] @ Wc1 + bc1), K=160, waves 0..3 ----
    if (wv < 4) {
        int m4 = wv & 1, c4 = wv >> 1;
        const short* B4 = Wc1t + (32 * c4 + m) * 16 + h * 8;
        const short* A4 = SEQ + (32 * m4 + m) * 136 + h * 8;
        float16 g4;
        #pragma unroll
        for (int i = 0; i < 16; ++i) g4[i] = 0.f;
        #pragma unroll
        for (int i = 0; i < 8; ++i) {
            short8 b = gld8(B4 + i * 1024);
            short8 a = lds8(A4 + i * 16);
            g4 = mfma16(a, b, g4);
        }
        const short* AF = featb + (size_t)(rowBase + 32 * m4 + m) * 32 + h * 8;
        g4 = mfma16(gld8(AF),      gld8(B4 + 8 * 1024), g4);
        g4 = mfma16(gld8(AF + 16), gld8(B4 + 9 * 1024), g4);
        float bb = bc1f[32 * c4 + m];
        #pragma unroll
        for (int r = 0; r < 16; ++r)
            C1[(32 * m4 + rowof(r, h)) * 72 + 32 * c4 + m] = f2bf(fmaxf(g4[r] + bb, 0.f));
    }
    __syncthreads();

    // ---- G5: c2 = relu(c1 @ Wc2 + bc2) -> C2 f32, waves 0..1 ----
    if (wv < 2) {
        const short* B5 = Wc2t + m * 16 + h * 8;
        const short* A5 = C1 + (wv * 32 + m) * 72 + h * 8;
        float16 g5;
        #pragma unroll
        for (int i = 0; i < 16; ++i) g5[i] = 0.f;
        #pragma unroll
        for (int i = 0; i < 4; ++i) {
            short8 b = gld8(B5 + i * 512);
            short8 a = lds8(A5 + i * 16);
            g5 = mfma16(a, b, g5);
        }
        float bb = bc2f[m];
        #pragma unroll
        for (int r = 0; r < 16; ++r)
            C2[(wv * 32 + rowof(r, h)) * 33 + m] = fmaxf(g5[r] + bb, 0.f);
    }
    __syncthreads();

    // ---- final: out = sigmoid(c2 . Wc3 + bc3) ----
    if (tid < 64) {
        float z = bc3f[0];
        #pragma unroll
        for (int i = 0; i < 32; ++i) z += C2[tid * 33 + i] * Wc3f[i];
        out[rowBase + tid] = 1.0f / (1.0f + expf(-z));
    }
}

// ---------------- fallback fused (verbatim verified fused_v4) ----------------
__global__ __launch_bounds__(512, 4)
void fused_v4(const float* __restrict__ x,
              const float* __restrict__ b1f, const float* __restrict__ b2f,
              const float* __restrict__ b3f, const float* __restrict__ Wsf,
              const float* __restrict__ bsf, const float* __restrict__ bc1f,
              const float* __restrict__ bc2f, const float* __restrict__ Wc3f,
              const float* __restrict__ bc3f,
              const short* __restrict__ wsw, float* __restrict__ out)
{
    __shared__ __align__(16) char smem[65536];
    short* XT    = (short*)smem;               // [64][376] bf16 x-tile (48128 B)
    short* SB    = (short*)(smem + 48128);     // [64][136] staging (17408 B)
    short* C1    = (short*)smem;               // [64][72]  (aliases XT, x dead)
    short* FEATL = (short*)(smem + 12288);     // [64][40]  (aliases XT)
    float* C2    = (float*)(smem + 20480);     // [64][33]  f32 (aliases XT)

    const short* W1t  = wsw + W1T_OFF;
    const short* W2t  = wsw + W2T_OFF;
    const short* W3t  = wsw + W3T_OFF;
    const short* Wc1t = wsw + WC1T_OFF;
    const short* Wc2t = wsw + WC2T_OFF;

    const int tid  = (int)threadIdx.x;
    const int lane = tid & 63;
    const int wv   = tid >> 6;
    const int m    = lane & 31;
    const int h    = lane >> 5;
    const int rowBase = (int)blockIdx.x * 64;

    float bb1a = b1f[32 * wv + m];
    float bb1b = b1f[256 + 32 * wv + m];
    float bb2  = b2f[32 * wv + m];
    float bb3  = b3f[32 * (wv & 3) + m];

    const int r0 = tid >> 3, j0 = tid & 7;
    const float* xrow = x + (size_t)(rowBase + r0) * 365;
    float s1 = 0.f, s2 = 0.f, s3 = 0.f, s4 = 0.f, mn = 1e30f, mx = -1e30f;
    #pragma unroll
    for (int i = 0; i < 6; ++i) {
        int o = j0 + 8 * i;
        if (o <= 45) {
            float xf[8];
            #pragma unroll
            for (int jj = 0; jj < 8; ++jj) {
                int col = o * 8 + jj;
                xf[jj] = (col < 365) ? xrow[col] : 0.f;
            }
            #pragma unroll
            for (int jj = 0; jj < 8; ++jj) {
                int col = o * 8 + jj;
                if (col < 365) {
                    float v = xf[jj], v2 = v * v;
                    s1 += v; s2 += v2; s3 += v2 * v; s4 += v2 * v2;
                    mn = fminf(mn, v); mx = fmaxf(mx, v);
                }
            }
            int4 w4;
            w4.x = (int)pk2(xf[0], xf[1]); w4.y = (int)pk2(xf[2], xf[3]);
            w4.z = (int)pk2(xf[4], xf[5]); w4.w = (int)pk2(xf[6], xf[7]);
            *(int4*)(XT + r0 * 376 + o * 8) = w4;
        }
    }
    #pragma unroll
    for (int off = 1; off <= 4; off <<= 1) {
        s1 += __shfl_xor(s1, off); s2 += __shfl_xor(s2, off);
        s3 += __shfl_xor(s3, off); s4 += __shfl_xor(s4, off);
        mn = fminf(mn, __shfl_xor(mn, off)); mx = fmaxf(mx, __shfl_xor(mx, off));
    }
    unsigned fdw0, fdw1;
    {
        float mean  = s1 * (1.0f / 365.0f);
        float var1  = (s2 - 365.0f * mean * mean) * (1.0f / 364.0f);
        float sigma = sqrtf(var1);
        float m3 = (s3 - 3.0f * mean * s2) * (1.0f / 365.0f) + 2.0f * mean * mean * mean;
        float mm = mean * mean;
        float m4 = (s4 - 4.0f * mean * s3 + 6.0f * mm * s2) * (1.0f / 365.0f) - 3.0f * mm * mm;
        float sg2 = sigma * sigma;
        float skew = m3 / (sigma * sg2 + 1e-8f);
        float kurt = m4 / (sg2 * sg2 + 1e-8f);
        float st[6] = { mean, sigma, mn, mx, skew, kurt };
        float f[4];
        #pragma unroll
        for (int c0 = 0; c0 < 4; ++c0) {
            int c = 4 * j0 + c0;
            float acc = bsf[c];
            #pragma unroll
            for (int jj = 0; jj < 6; ++jj) acc += st[jj] * Wsf[jj * 32 + c];
            f[c0] = acc;
        }
        fdw0 = pk2(f[0], f[1]); fdw1 = pk2(f[2], f[3]);
    }
    __syncthreads();

    float16 ha0, ha1;
    #pragma unroll
    for (int i = 0; i < 16; ++i) { ha0[i] = 0.f; ha1[i] = 0.f; }

    const short* Ap0  = XT + m * 376 + h * 8;
    const short* Ap1  = XT + (32 + m) * 376 + h * 8;
    const short* A2p0 = SB + m * 136 + h * 8;
    const short* A2p1 = SB + (32 + m) * 136 + h * 8;
    const int stcol = 32 * (wv & 3) + m;

    #pragma unroll
    for (int p = 0; p < 2; ++p) {
        float16 ga0, ga1;
        #pragma unroll
        for (int i = 0; i < 16; ++i) { ga0[i] = 0.f; ga1[i] = 0.f; }
        const short* B1 = W1t + (256 * p + 32 * wv + m) * 16 + h * 8;
        #pragma unroll
        for (int kc = 0; kc < 23; ++kc) {
            short8 b  = gld8(B1 + kc * 8192);
            short8 a0 = lds8(Ap0 + kc * 16);
            short8 a1 = lds8(Ap1 + kc * 16);
            ga0 = mfma16(a0, b, ga0);
            ga1 = mfma16(a1, b, ga1);
        }
        float bb = p ? bb1b : bb1a;
        #pragma unroll
        for (int s = 0; s < 2; ++s) {
            int sl = 2 * p + s;
            __syncthreads();
            if ((wv >> 2) == s) {
                #pragma unroll
                for (int r = 0; r < 16; ++r) {
                    SB[rowof(r, h) * 136 + stcol]        = f2bf(fmaxf(ga0[r] + bb, 0.f));
                    SB[(32 + rowof(r, h)) * 136 + stcol] = f2bf(fmaxf(ga1[r] + bb, 0.f));
                }
            }
            __syncthreads();
            const short* B2 = W2t + sl * 8 * 4096 + (32 * wv + m) * 16 + h * 8;
            #pragma unroll
            for (int i = 0; i < 8; ++i) {
                short8 b  = gld8(B2 + i * 4096);
                short8 a0 = lds8(A2p0 + i * 16);
                short8 a1 = lds8(A2p1 + i * 16);
                ha0 = mfma16(a0, b, ha0);
                ha1 = mfma16(a1, b, ha1);
            }
        }
    }

    float16 g3;
    #pragma unroll
    for (int i = 0; i < 16; ++i) g3[i] = 0.f;
    const short* A3p = SB + ((wv >> 2) * 32 + m) * 136 + h * 8;
    #pragma unroll
    for (int t = 0; t < 2; ++t) {
        __syncthreads();
        if ((wv >> 2) == t) {
            #pragma unroll
            for (int r = 0; r < 16; ++r) {
                SB[rowof(r, h) * 136 + stcol]        = f2bf(fmaxf(ha0[r] + bb2, 0.f));
                SB[(32 + rowof(r, h)) * 136 + stcol] = f2bf(fmaxf(ha1[r] + bb2, 0.f));
            }
        }
        __syncthreads();
        const short* B3 = W3t + t * 8 * 2048 + (32 * (wv & 3) + m) * 16 + h * 8;
        #pragma unroll
        for (int i = 0; i < 8; ++i) {
            short8 b = gld8(B3 + i * 2048);
            short8 a = lds8(A3p + i * 16);
            g3 = mfma16(a, b, g3);
        }
    }

    __syncthreads();
    {
        int rb = (wv >> 2) * 32;
        #pragma unroll
        for (int r = 0; r < 16; ++r)
            SB[(rb + rowof(r, h)) * 136 + stcol] = f2bf(fmaxf(g3[r] + bb3, 0.f));
        *(unsigned*)(FEATL + r0 * 40 + 4 * j0)     = fdw0;
        *(unsigned*)(FEATL + r0 * 40 + 4 * j0 + 2) = fdw1;
    }
    __syncthreads();

    if (wv < 4) {
        int m4 = wv & 1, c4 = wv >> 1;
        const short* B4 = Wc1t + (32 * c4 + m) * 16 + h * 8;
        const short* A4 = SB + (m4 * 32 + m) * 136 + h * 8;
        float16 g4;
        #pragma unroll
        for (int i = 0; i < 16; ++i) g4[i] = 0.f;
        #pragma unroll
        for (int i = 0; i < 8; ++i) {
            short8 b = gld8(B4 + i * 1024);
            short8 a = lds8(A4 + i * 16);
            g4 = mfma16(a, b, g4);
        }
        const short* AF = FEATL + (m4 * 32 + m) * 40 + h * 8;
        #pragma unroll
        for (int i = 0; i < 2; ++i) {
            short8 b = gld8(B4 + (8 + i) * 1024);
            short8 a = lds8(AF + i * 16);
            g4 = mfma16(a, b, g4);
        }
        float bb = bc1f[32 * c4 + m];
        #pragma unroll
        for (int r = 0; r < 16; ++r)
            C1[(m4 * 32 + rowof(r, h)) * 72 + 32 * c4 + m] = f2bf(fmaxf(g4[r] + bb, 0.f));
    }
    __syncthreads();

    if (wv < 2) {
        const short* B5 = Wc2t + m * 16 + h * 8;
        const short* A5 = C1 + (wv * 32 + m) * 72 + h * 8;
        float16 g5;
        #pragma unroll
        for (int i = 0; i < 16; ++i) g5[i] = 0.f;
        #pragma unroll
        for (int i = 0; i < 4; ++i) {
            short8 b = gld8(B5 + i * 512);
            short8 a = lds8(A5 + i * 16);
            g5 = mfma16(a, b, g5);
        }
        float bb = bc2f[m];
        #pragma unroll
        for (int r = 0; r < 16; ++r)
            C2[(wv * 32 + rowof(r, h)) * 33 + m] = fmaxf(g5[r] + bb, 0.f);
    }
    __syncthreads();

    if (tid < 64) {
        float z = bc3f[0];
        #pragma unroll
        for (int i = 0; i < 32; ++i) z += C2[tid * 33 + i] * Wc3f[i];
        out[rowBase + tid] = 1.0f / (1.0f + expf(-z));
    }
}

extern "C" void kernel_launch(void* const* d_in, const int* in_sizes, int n_in,
                              void* d_out, int out_size, void* d_ws, size_t ws_size,
                              hipStream_t stream)
{
    (void)in_sizes; (void)n_in; (void)out_size;
    const float* x   = (const float*)d_in[0];
    const float* W1  = (const float*)d_in[1];
    const float* b1  = (const float*)d_in[2];
    const float* W2  = (const float*)d_in[3];
    const float* b2  = (const float*)d_in[4];
    const float* W3  = (const float*)d_in[5];
    const float* b3  = (const float*)d_in[6];
    const float* Ws  = (const float*)d_in[7];
    const float* bs  = (const float*)d_in[8];
    const float* Wc1 = (const float*)d_in[9];
    const float* bc1 = (const float*)d_in[10];
    const float* Wc2 = (const float*)d_in[11];
    const float* bc2 = (const float*)d_in[12];
    const float* Wc3 = (const float*)d_in[13];
    const float* bc3 = (const float*)d_in[14];
    short* ws = (short*)d_ws;

    if (ws_size >= WS_NEED_BYTES) {
        // big-ws path: prep does weights + x->bf16 + moments/FEAT; fused is pure MFMA
        prep_all<<<358 + 16384, 256, 0, stream>>>(W1, W2, W3, Wc1, Wc2, x, Ws, bs, ws);
        fused_v5<<<1024, 512, 0, stream>>>(b1, b2, b3, bc1, bc2, Wc3, bc3,
                                           ws, (float*)d_out);
    } else {
        // fallback: verified v4 pipeline
        prep_all<<<358, 256, 0, stream>>>(W1, W2, W3, Wc1, Wc2, x, Ws, bs, ws);
        fused_v4<<<1024, 512, 0, stream>>>(x, b1, b2, b3, Ws, bs, bc1, bc2, Wc3, bc3,
                                           ws, (float*)d_out);
    }
}

// Round 3
// 215.087 us; speedup vs baseline: 1.3008x; 1.3008x over previous
//
#include <hip/hip_runtime.h>
#include <math.h>

typedef __attribute__((ext_vector_type(8)))  short short8;   // 8 x bf16 (4 VGPR) MFMA operand
typedef __attribute__((ext_vector_type(16))) float float16;  // 32x32 MFMA accumulator

#define DEVI __device__ __forceinline__

DEVI short f2bf(float f) {                      // RNE float -> bf16 bits
    unsigned u = __float_as_uint(f);
    u = (u + 0x7fffu + ((u >> 16) & 1u)) >> 16;
    return (short)u;
}
DEVI unsigned pk2(float a, float b) {
    return (unsigned)(unsigned short)f2bf(a) | ((unsigned)(unsigned short)f2bf(b) << 16);
}
DEVI float16 mfma16(short8 a, short8 b, float16 c) {
    return __builtin_amdgcn_mfma_f32_32x32x16_bf16(a, b, c, 0, 0, 0);
}
// C/D row for reg r, half h: row = (r&3) + 8*(r>>2) + 4*h  [verified]
DEVI int rowof(int r, int h) { return (r & 3) + 8 * (r >> 2) + 4 * h; }
DEVI short8 lds8(const short* p) { return *(const short8*)p; }
DEVI short8 gld8(const short* p) { return *(const short8*)p; }

// ---- ws layout (shorts): MFMA-native [ceil(K/16)][N][16] bf16 ----
#define W1T_OFF  0          // [23][512][16] (K=365 pad 368)
#define W2T_OFF  188416     // [32][256][16]
#define W3T_OFF  319488     // [16][128][16]
#define WC1T_OFF 352256     // [10][64][16]
#define WC2T_OFF 362496     // [4][32][16]

// ---------------- prologue: coalesced weight transpose via LDS tiles ---------
__global__ void prep_v2(const float* __restrict__ W1, const float* __restrict__ W2,
                        const float* __restrict__ W3, const float* __restrict__ Wc1,
                        const float* __restrict__ Wc2, short* __restrict__ ws) {
    __shared__ short T[16 * 72];
    int b = blockIdx.x, t = threadIdx.x;
    const float* src; int K, N; size_t base; int kc, nb;
    if (b < 184)        {            src = W1;  K = 365; N = 512; base = W1T_OFF;  kc = b >> 3;  nb = b & 7; }
    else if (b < 312)   { int l = b - 184; src = W2;  K = 512; N = 256; base = W2T_OFF;  kc = l >> 2;  nb = l & 3; }
    else if (b < 344)   { int l = b - 312; src = W3;  K = 256; N = 128; base = W3T_OFF;  kc = l >> 1;  nb = l & 1; }
    else if (b < 354)   {            src = Wc1; K = 160; N = 64;  base = WC1T_OFF; kc = b - 344; nb = 0; }
    else                {            src = Wc2; K = 64;  N = 32;  base = WC2T_OFF; kc = b - 354; nb = 0; }
    int n = nb * 64 + (t & 63);
    int kr = t >> 6;
    #pragma unroll
    for (int i = 0; i < 4; ++i) {
        int krow = kr + 4 * i;
        int k = kc * 16 + krow;
        float v = (k < K && n < N) ? src[(size_t)k * N + n] : 0.f;
        T[krow * 72 + (t & 63)] = f2bf(v);
    }
    __syncthreads();
    int n2 = t >> 2, ksq = (t & 3) * 4;
    int ng = nb * 64 + n2;
    if (ng < N) {
        unsigned lo = (unsigned)(unsigned short)T[ksq * 72 + n2]
                    | ((unsigned)(unsigned short)T[(ksq + 1) * 72 + n2] << 16);
        unsigned hi = (unsigned)(unsigned short)T[(ksq + 2) * 72 + n2]
                    | ((unsigned)(unsigned short)T[(ksq + 3) * 72 + n2] << 16);
        uint2 d; d.x = lo; d.y = hi;
        *(uint2*)(ws + base + ((size_t)kc * N + ng) * 16 + ksq) = d;
    }
}

// ---------------- fused main: BM=64, 1024 blocks x 512 threads ----------------
// v6 = verified v4 with ONE change: FEATL is a dedicated LDS region (no longer
// aliasing XT), and fdw0/fdw1 are stored to it immediately after the stats
// phase (pre-G1). This kills the only register live range spanning the whole
// GEMM — the hypothesized source of v4's 39 MB of scratch-spill writes.
__global__ __launch_bounds__(512, 4)
void fused_v6(const float* __restrict__ x,
              const float* __restrict__ b1f, const float* __restrict__ b2f,
              const float* __restrict__ b3f, const float* __restrict__ Wsf,
              const float* __restrict__ bsf, const float* __restrict__ bc1f,
              const float* __restrict__ bc2f, const float* __restrict__ Wc3f,
              const float* __restrict__ bc3f,
              const short* __restrict__ wsw, float* __restrict__ out)
{
    __shared__ __align__(16) char smem[70656];
    short* XT    = (short*)smem;               // [64][376] bf16 x-tile (48128 B)
    short* SB    = (short*)(smem + 48128);     // [64][136] staging (17408 B)
    short* FEATL = (short*)(smem + 65536);     // [64][40]  (5120 B, DEDICATED)
    short* C1    = (short*)smem;               // [64][72]  (aliases XT, x dead)
    float* C2    = (float*)(smem + 20480);     // [64][33]  f32 (aliases XT)

    const short* W1t  = wsw + W1T_OFF;
    const short* W2t  = wsw + W2T_OFF;
    const short* W3t  = wsw + W3T_OFF;
    const short* Wc1t = wsw + WC1T_OFF;
    const short* Wc2t = wsw + WC2T_OFF;

    const int tid  = (int)threadIdx.x;
    const int lane = tid & 63;
    const int wv   = tid >> 6;       // 0..7 = col-group owner (dup-free B)
    const int m    = lane & 31;
    const int h    = lane >> 5;
    const int rowBase = (int)blockIdx.x * 64;

    // bias prefetch (overlaps x-phase)
    float bb1a = b1f[32 * wv + m];
    float bb1b = b1f[256 + 32 * wv + m];
    float bb2  = b2f[32 * wv + m];
    float bb3  = b3f[32 * (wv & 3) + m];

    // ---- fill XT + fused row moments (plain loads; x stays L3-resident) ----
    const int r0 = tid >> 3, j0 = tid & 7;
    const float* xrow = x + (size_t)(rowBase + r0) * 365;
    float s1 = 0.f, s2 = 0.f, s3 = 0.f, s4 = 0.f, mn = 1e30f, mx = -1e30f;
    #pragma unroll
    for (int i = 0; i < 6; ++i) {
        int o = j0 + 8 * i;
        if (o <= 45) {
            float xf[8];
            #pragma unroll
            for (int jj = 0; jj < 8; ++jj) {
                int col = o * 8 + jj;
                xf[jj] = (col < 365) ? xrow[col] : 0.f;
            }
            #pragma unroll
            for (int jj = 0; jj < 8; ++jj) {
                int col = o * 8 + jj;
                if (col < 365) {
                    float v = xf[jj], v2 = v * v;
                    s1 += v; s2 += v2; s3 += v2 * v; s4 += v2 * v2;
                    mn = fminf(mn, v); mx = fmaxf(mx, v);
                }
            }
            int4 w4;
            w4.x = (int)pk2(xf[0], xf[1]); w4.y = (int)pk2(xf[2], xf[3]);
            w4.z = (int)pk2(xf[4], xf[5]); w4.w = (int)pk2(xf[6], xf[7]);
            *(int4*)(XT + r0 * 376 + o * 8) = w4;
        }
    }
    #pragma unroll
    for (int off = 1; off <= 4; off <<= 1) {
        s1 += __shfl_xor(s1, off); s2 += __shfl_xor(s2, off);
        s3 += __shfl_xor(s3, off); s4 += __shfl_xor(s4, off);
        mn = fminf(mn, __shfl_xor(mn, off)); mx = fmaxf(mx, __shfl_xor(mx, off));
    }
    {
        float mean  = s1 * (1.0f / 365.0f);
        float var1  = (s2 - 365.0f * mean * mean) * (1.0f / 364.0f);
        float sigma = sqrtf(var1);
        float m3 = (s3 - 3.0f * mean * s2) * (1.0f / 365.0f) + 2.0f * mean * mean * mean;
        float mm = mean * mean;
        float m4 = (s4 - 4.0f * mean * s3 + 6.0f * mm * s2) * (1.0f / 365.0f) - 3.0f * mm * mm;
        float sg2 = sigma * sigma;
        float skew = m3 / (sigma * sg2 + 1e-8f);
        float kurt = m4 / (sg2 * sg2 + 1e-8f);
        float st[6] = { mean, sigma, mn, mx, skew, kurt };
        float f[4];
        #pragma unroll
        for (int c0 = 0; c0 < 4; ++c0) {
            int c = 4 * j0 + c0;
            float acc = bsf[c];
            #pragma unroll
            for (int jj = 0; jj < 6; ++jj) acc += st[jj] * Wsf[jj * 32 + c];
            f[c0] = acc;
        }
        // store feat NOW — dedicated region, frees all stats registers pre-G1
        *(unsigned*)(FEATL + r0 * 40 + 4 * j0)     = pk2(f[0], f[1]);
        *(unsigned*)(FEATL + r0 * 40 + 4 * j0 + 2) = pk2(f[2], f[3]);
    }
    __syncthreads();                            // XT (+FEATL) ready

    // ---- G1 (2 passes of 256 cols, dup-free) interleaved with G2 slabs ----
    float16 ha0, ha1;                           // h2 rows 0-31 / 32-63, cols 32wv..+32
    #pragma unroll
    for (int i = 0; i < 16; ++i) { ha0[i] = 0.f; ha1[i] = 0.f; }

    const short* Ap0  = XT + m * 376 + h * 8;
    const short* Ap1  = XT + (32 + m) * 376 + h * 8;
    const short* A2p0 = SB + m * 136 + h * 8;
    const short* A2p1 = SB + (32 + m) * 136 + h * 8;
    const int stcol = 32 * (wv & 3) + m;        // staging col for writer waves

    #pragma unroll
    for (int p = 0; p < 2; ++p) {
        float16 ga0, ga1;
        #pragma unroll
        for (int i = 0; i < 16; ++i) { ga0[i] = 0.f; ga1[i] = 0.f; }
        const short* B1 = W1t + (256 * p + 32 * wv + m) * 16 + h * 8;
        #pragma unroll
        for (int kc = 0; kc < 23; ++kc) {
            short8 b  = gld8(B1 + kc * 8192);
            short8 a0 = lds8(Ap0 + kc * 16);
            short8 a1 = lds8(Ap1 + kc * 16);
            ga0 = mfma16(a0, b, ga0);
            ga1 = mfma16(a1, b, ga1);
        }
        float bb = p ? bb1b : bb1a;
        #pragma unroll
        for (int s = 0; s < 2; ++s) {
            int sl = 2 * p + s;
            __syncthreads();                    // prior SB consumers done
            if ((wv >> 2) == s) {               // waves [4s,4s+4) stage their cols
                #pragma unroll
                for (int r = 0; r < 16; ++r) {
                    SB[rowof(r, h) * 136 + stcol]        = f2bf(fmaxf(ga0[r] + bb, 0.f));
                    SB[(32 + rowof(r, h)) * 136 + stcol] = f2bf(fmaxf(ga1[r] + bb, 0.f));
                }
            }
            __syncthreads();                    // slab staged
            const short* B2 = W2t + sl * 8 * 4096 + (32 * wv + m) * 16 + h * 8;
            #pragma unroll
            for (int i = 0; i < 8; ++i) {
                short8 b  = gld8(B2 + i * 4096);
                short8 a0 = lds8(A2p0 + i * 16);
                short8 a1 = lds8(A2p1 + i * 16);
                ha0 = mfma16(a0, b, ha0);
                ha1 = mfma16(a1, b, ha1);
            }
        }
    }

    // ---- G3: seq = relu(h2 @ W3 + b3), K=256 via 2 staged slabs ----
    float16 g3;
    #pragma unroll
    for (int i = 0; i < 16; ++i) g3[i] = 0.f;
    const short* A3p = SB + ((wv >> 2) * 32 + m) * 136 + h * 8;
    #pragma unroll
    for (int t = 0; t < 2; ++t) {
        __syncthreads();
        if ((wv >> 2) == t) {                   // stage h2 cols [128t,128t+128)
            #pragma unroll
            for (int r = 0; r < 16; ++r) {
                SB[rowof(r, h) * 136 + stcol]        = f2bf(fmaxf(ha0[r] + bb2, 0.f));
                SB[(32 + rowof(r, h)) * 136 + stcol] = f2bf(fmaxf(ha1[r] + bb2, 0.f));
            }
        }
        __syncthreads();
        const short* B3 = W3t + t * 8 * 2048 + (32 * (wv & 3) + m) * 16 + h * 8;
        #pragma unroll
        for (int i = 0; i < 8; ++i) {
            short8 b = gld8(B3 + i * 2048);
            short8 a = lds8(A3p + i * 16);
            g3 = mfma16(a, b, g3);
        }
    }

    // ---- stage seq (full [64][128]) ----
    __syncthreads();
    {
        int rb = (wv >> 2) * 32;
        #pragma unroll
        for (int r = 0; r < 16; ++r)
            SB[(rb + rowof(r, h)) * 136 + stcol] = f2bf(fmaxf(g3[r] + bb3, 0.f));
    }
    __syncthreads();

    // ---- G4: c1 = relu([seq|feat] @ Wc1 + bc1), K=160, waves 0..3 ----
    if (wv < 4) {
        int m4 = wv & 1, c4 = wv >> 1;
        const short* B4 = Wc1t + (32 * c4 + m) * 16 + h * 8;
        const short* A4 = SB + (m4 * 32 + m) * 136 + h * 8;
        float16 g4;
        #pragma unroll
        for (int i = 0; i < 16; ++i) g4[i] = 0.f;
        #pragma unroll
        for (int i = 0; i < 8; ++i) {
            short8 b = gld8(B4 + i * 1024);
            short8 a = lds8(A4 + i * 16);
            g4 = mfma16(a, b, g4);
        }
        const short* AF = FEATL + (m4 * 32 + m) * 40 + h * 8;
        #pragma unroll
        for (int i = 0; i < 2; ++i) {
            short8 b = gld8(B4 + (8 + i) * 1024);
            short8 a = lds8(AF + i * 16);
            g4 = mfma16(a, b, g4);
        }
        float bb = bc1f[32 * c4 + m];
        #pragma unroll
        for (int r = 0; r < 16; ++r)
            C1[(m4 * 32 + rowof(r, h)) * 72 + 32 * c4 + m] = f2bf(fmaxf(g4[r] + bb, 0.f));
    }
    __syncthreads();

    // ---- G5: c2 = relu(c1 @ Wc2 + bc2) -> C2 f32, waves 0..1 ----
    if (wv < 2) {
        const short* B5 = Wc2t + m * 16 + h * 8;
        const short* A5 = C1 + (wv * 32 + m) * 72 + h * 8;
        float16 g5;
        #pragma unroll
        for (int i = 0; i < 16; ++i) g5[i] = 0.f;
        #pragma unroll
        for (int i = 0; i < 4; ++i) {
            short8 b = gld8(B5 + i * 512);
            short8 a = lds8(A5 + i * 16);
            g5 = mfma16(a, b, g5);
        }
        float bb = bc2f[m];
        #pragma unroll
        for (int r = 0; r < 16; ++r)
            C2[(wv * 32 + rowof(r, h)) * 33 + m] = fmaxf(g5[r] + bb, 0.f);
    }
    __syncthreads();

    // ---- final: out = sigmoid(c2 . Wc3 + bc3) ----
    if (tid < 64) {
        float z = bc3f[0];
        #pragma unroll
        for (int i = 0; i < 32; ++i) z += C2[tid * 33 + i] * Wc3f[i];
        out[rowBase + tid] = 1.0f / (1.0f + expf(-z));
    }
}

extern "C" void kernel_launch(void* const* d_in, const int* in_sizes, int n_in,
                              void* d_out, int out_size, void* d_ws, size_t ws_size,
                              hipStream_t stream)
{
    (void)in_sizes; (void)n_in; (void)out_size; (void)ws_size;
    const float* x   = (const float*)d_in[0];
    const float* W1  = (const float*)d_in[1];
    const float* b1  = (const float*)d_in[2];
    const float* W2  = (const float*)d_in[3];
    const float* b2  = (const float*)d_in[4];
    const float* W3  = (const float*)d_in[5];
    const float* b3  = (const float*)d_in[6];
    const float* Ws  = (const float*)d_in[7];
    const float* bs  = (const float*)d_in[8];
    const float* Wc1 = (const float*)d_in[9];
    const float* bc1 = (const float*)d_in[10];
    const float* Wc2 = (const float*)d_in[11];
    const float* bc2 = (const float*)d_in[12];
    const float* Wc3 = (const float*)d_in[13];
    const float* bc3 = (const float*)d_in[14];
    short* ws = (short*)d_ws;

    prep_v2<<<358, 256, 0, stream>>>(W1, W2, W3, Wc1, Wc2, ws);
    fused_v6<<<1024, 512, 0, stream>>>(x, b1, b2, b3, Ws, bs, bc1, bc2, Wc3, bc3,
                                       ws, (float*)d_out);
}